// Round 8
// baseline (24219.757 us; speedup 1.0000x reference)
//
#include <hip/hip_runtime.h>
#include <hip/hip_bf16.h>
#include <math.h>

#define T_LEN   8192
#define D_IN    1024
#define H_DIM   1024
#define G4      4096      // 4*H
#define K_TAG   16
#define NWG     128       // workgroups in persistent LSTM kernel
#define NPAIR   512       // h exchange slots (2 bf16 per slot)
#define NC      128       // CRF chunks
#define CLEN    64        // steps per CRF chunk
#define NEGINF_V (-100000.0f)

// fast nonlinearities: __expf (native v_exp path) + fast divide.
// sigmoid: inf-safe without clamp (e=inf -> fdiv(1,inf)=0).
// tanh: clamp 2x to +-88 so e stays finite (tanh saturates anyway).
__device__ __forceinline__ float fsig(float x) {
  return __fdividef(1.f, 1.f + __expf(-x));
}
__device__ __forceinline__ float ftanh(float x) {
  float e = __expf(fminf(fmaxf(2.f * x, -88.f), 88.f));
  return __fdividef(e - 1.f, e + 1.f);
}

// ---------------------------------------------------------------------------
// init: bsum = b_ih + b_hh; h_all[0] = 0; htag[2][512] = {tag 0, 2x bf16 0}
// MUST run every launch: graph replays would otherwise see stale tags.
// ---------------------------------------------------------------------------
__global__ void k_init(const float* __restrict__ b_ih, const float* __restrict__ b_hh,
                       float* __restrict__ bsum, float* __restrict__ h0,
                       unsigned long long* __restrict__ htag) {
  int tid = blockIdx.x * 256 + threadIdx.x;
  if (tid < G4) bsum[tid] = b_ih[tid] + b_hh[tid];
  if (tid < H_DIM) h0[tid] = 0.f;
  if (tid < 2 * NPAIR) htag[tid] = 0ULL;   // tag=0, h pair = bf16 zeros
}

// ---------------------------------------------------------------------------
// GEMM: xg[t][n] = sum_d seq[t][d]*W_ih[n][d] + bsum[n], stored bf16.
// 128x128 tile, K-tile 16, 256 threads, 8x8 per thread, fp32 vector ALU.
// ---------------------------------------------------------------------------
__global__ __launch_bounds__(256) void k_gemm_xg(
    const float* __restrict__ A,      // seq   (T, D)
    const float* __restrict__ B,      // W_ih  (4H, D)
    const float* __restrict__ bsum,   // (4H)
    __hip_bfloat16* __restrict__ xg)  // (T, 4H)
{
  __shared__ __align__(16) float As[16][132];
  __shared__ __align__(16) float Bs[16][132];
  const int tid = threadIdx.x;
  const int n0 = blockIdx.x * 128;   // 32 tiles
  const int m0 = blockIdx.y * 128;   // 64 tiles
  const int ty = tid >> 4, tx = tid & 15;
  float acc[8][8] = {};

  for (int k0 = 0; k0 < D_IN; k0 += 16) {
#pragma unroll
    for (int p0 = 0; p0 < 2; ++p0) {
      int p = tid + p0 * 256;              // 0..511 float4 slots
      int row = p >> 2;
      int c4 = (p & 3) * 4;
      float4 va = *(const float4*)&A[(size_t)(m0 + row) * D_IN + k0 + c4];
      As[c4 + 0][row] = va.x; As[c4 + 1][row] = va.y;
      As[c4 + 2][row] = va.z; As[c4 + 3][row] = va.w;
      float4 vb = *(const float4*)&B[(size_t)(n0 + row) * D_IN + k0 + c4];
      Bs[c4 + 0][row] = vb.x; Bs[c4 + 1][row] = vb.y;
      Bs[c4 + 2][row] = vb.z; Bs[c4 + 3][row] = vb.w;
    }
    __syncthreads();
#pragma unroll
    for (int k = 0; k < 16; ++k) {
      float4 a0 = *(const float4*)&As[k][ty * 8];
      float4 a1 = *(const float4*)&As[k][ty * 8 + 4];
      float4 b0 = *(const float4*)&Bs[k][tx * 8];
      float4 b1 = *(const float4*)&Bs[k][tx * 8 + 4];
      float av[8] = {a0.x, a0.y, a0.z, a0.w, a1.x, a1.y, a1.z, a1.w};
      float bv[8] = {b0.x, b0.y, b0.z, b0.w, b1.x, b1.y, b1.z, b1.w};
#pragma unroll
      for (int i = 0; i < 8; ++i)
#pragma unroll
        for (int j = 0; j < 8; ++j)
          acc[i][j] = fmaf(av[i], bv[j], acc[i][j]);
    }
    __syncthreads();
  }

#pragma unroll
  for (int i = 0; i < 8; ++i) {
    size_t m = (size_t)(m0 + ty * 8 + i);
    union { __hip_bfloat16 h[8]; uint4 v; } pk;
#pragma unroll
    for (int j = 0; j < 8; ++j)
      pk.h[j] = __float2bfloat16(acc[i][j] + bsum[n0 + tx * 8 + j]);
    *(uint4*)&xg[m * G4 + n0 + tx * 8] = pk.v;
  }
}

// ---------------------------------------------------------------------------
// Persistent LSTM recurrence — direct per-wave publish, wave0-only poll,
// ONE barrier per step, zero handshakes/fences.
//
// 128 WGs x 256 threads (4 waves). Wave v owns h elements j = 2v, 2v+1 of
// slice [w*8, w*8+8). Lane group rl8 = lane>>3 handles gate g = rl8>>1 of
// element b = rl8&1 (row = g*1024 + w*8 + 2v + b); lane covers columns
// sub*4 + 32k (k=0..31), weights in registers.
//
// Per step:
//   wave 0: poll 512 global slots (8 lane-contiguous u64 loads, s_sleep(1)
//           backoff) -> unpack to h_lds -> barrier -> matvec -> nonlin ->
//           lane 0 publishes {tag=t, bf16 pair} DIRECTLY (8 B agent-scope
//           store) -> loop to next poll.
//   waves 1-3: barrier -> matvec -> nonlin -> lane 0 publishes directly ->
//           fall through to t+1 xg prefetch + barrier wait.
//
// R8 change vs R7: the LDS handshake + wave0 relay publish are GONE — each
// wave's lane 0 stores its slot the moment its h is ready (publish enters
// the fabric ~200-400 cyc earlier; the longest-latency leg starts sooner).
//
// Correctness ledger:
//  - h_lds restage safety WITHOUT a second barrier: wave 0 restages only
//    after its poll sees ALL 512 slots at tag >= t; that includes our own
//    waves 1-3, whose publishes data-depend on their matvec (h_lds reads)
//    and are wave-synchronous with all 64 lanes via __shfl. So every
//    h_lds read of step t precedes any step-t+1 staging. One barrier
//    (post-staging) per step is the only sync.
//  - tag-in-word u64 slots => per-slot atomicity, no fences.
//  - own-slot poll may transiently miss our in-flight store -> retry, never
//    deadlock (store is issued before the poll loop, lands eventually).
//  - compiler: staging is control-dependent on the poll loads; explicit
//    compiler barrier after publish blocks LDS-store hoisting.
//  - global parity double-buffer: a slot can't reach tag t+1 while any
//    consumer still awaits t-1 (that publisher's WG must first have
//    detected tag >= t on ALL slots, which requires every consumer's
//    await of t-1 to have completed).
// ---------------------------------------------------------------------------
__global__ __launch_bounds__(256) void k_lstm(
    const float* __restrict__ W_hh,          // (4H, H)
    const __hip_bfloat16* __restrict__ xg,   // (T, 4H)
    float* __restrict__ h_all,               // (T+1, H) plain, for CRF kernels
    unsigned long long* __restrict__ htag)   // (2, 512) tagged bf16-pair slots
{
  __shared__ __align__(16) float h_lds[H_DIM];

  const int tid = threadIdx.x;
  const int w = blockIdx.x;
  const int lane = tid & 63;
  const int v = tid >> 6;                   // wave id 0..3
  const int rl8 = lane >> 3;                // 0..7
  const int sub = lane & 7;                 // 0..7 column chunk
  const int g = rl8 >> 1, b = rl8 & 1;
  const int j = 2 * v + b;                  // element within 8-slice
  const int grow = g * H_DIM + w * 8 + j;   // gate row in (4H)

  float4 w4[32];
#pragma unroll
  for (int k = 0; k < 32; ++k)
    w4[k] = *(const float4*)&W_hh[(size_t)grow * H_DIM + sub * 4 + 32 * k];

  float c_reg = 0.f;   // cell state, redundantly maintained by all lanes

  for (int t = 1; t <= T_LEN; ++t) {
    // prefetch this step's input-gate term (independent of exchange;
    // for waves 1-3 this issues while wave 0 still polls)
    float xgv = __bfloat162float(xg[(size_t)(t - 1) * G4 + grow]);

    if (v == 0) {
      // ---- wave 0: poll all 512 tagged slots of parity (t-1)&1 ----
      unsigned long long* hb = htag + (((t - 1) & 1) << 9);
      const unsigned tgt = (unsigned)(t - 1);
      unsigned long long x0, x1, x2, x3, x4, x5, x6, x7;
      for (;;) {
        x0 = __hip_atomic_load(hb + lane,       __ATOMIC_RELAXED, __HIP_MEMORY_SCOPE_AGENT);
        x1 = __hip_atomic_load(hb + lane + 64,  __ATOMIC_RELAXED, __HIP_MEMORY_SCOPE_AGENT);
        x2 = __hip_atomic_load(hb + lane + 128, __ATOMIC_RELAXED, __HIP_MEMORY_SCOPE_AGENT);
        x3 = __hip_atomic_load(hb + lane + 192, __ATOMIC_RELAXED, __HIP_MEMORY_SCOPE_AGENT);
        x4 = __hip_atomic_load(hb + lane + 256, __ATOMIC_RELAXED, __HIP_MEMORY_SCOPE_AGENT);
        x5 = __hip_atomic_load(hb + lane + 320, __ATOMIC_RELAXED, __HIP_MEMORY_SCOPE_AGENT);
        x6 = __hip_atomic_load(hb + lane + 384, __ATOMIC_RELAXED, __HIP_MEMORY_SCOPE_AGENT);
        x7 = __hip_atomic_load(hb + lane + 448, __ATOMIC_RELAXED, __HIP_MEMORY_SCOPE_AGENT);
        unsigned mn = min(min(min((unsigned)(x0 >> 32), (unsigned)(x1 >> 32)),
                              min((unsigned)(x2 >> 32), (unsigned)(x3 >> 32))),
                          min(min((unsigned)(x4 >> 32), (unsigned)(x5 >> 32)),
                              min((unsigned)(x6 >> 32), (unsigned)(x7 >> 32))));
        if (mn >= tgt) break;
        __builtin_amdgcn_s_sleep(1);
      }
      // unpack bf16 pairs -> h_lds (float2 per slot; 2-way bank alias, free)
      unsigned long long xs[8] = {x0, x1, x2, x3, x4, x5, x6, x7};
#pragma unroll
      for (int i = 0; i < 8; ++i) {
        unsigned lo = (unsigned)xs[i];
        unsigned short s0 = (unsigned short)lo;
        unsigned short s1 = (unsigned short)(lo >> 16);
        float2 p;
        p.x = __bfloat162float(*(const __hip_bfloat16*)&s0);
        p.y = __bfloat162float(*(const __hip_bfloat16*)&s1);
        ((float2*)h_lds)[lane + 64 * i] = p;
      }
    }
    __syncthreads();   // the ONLY barrier: h_{t-1} staged for all waves

    // ---- matvec: 128 columns per thread ----
    const float4* h4 = (const float4*)h_lds;
    float acc = 0.f;
#pragma unroll
    for (int k = 0; k < 32; ++k) {
      float4 hv = h4[sub + 8 * k];
      acc = fmaf(w4[k].x, hv.x, acc);
      acc = fmaf(w4[k].y, hv.y, acc);
      acc = fmaf(w4[k].z, hv.z, acc);
      acc = fmaf(w4[k].w, hv.w, acc);
    }
    acc += __shfl_xor(acc, 1);
    acc += __shfl_xor(acc, 2);
    acc += __shfl_xor(acc, 4);
    acc += xgv;                       // all 8 lanes of the group hold the gate

    // ---- gather i,f,g,o of this lane's element (b = (lane>>3)&1) ----
    const int bl = lane & 8;
    float gi = __shfl(acc, bl);
    float gf = __shfl(acc, bl | 16);
    float gg = __shfl(acc, bl | 32);
    float go = __shfl(acc, bl | 48);

    float si = fsig(gi);
    float sf = fsig(gf);
    float so = fsig(go);
    c_reg = sf * c_reg + si * ftanh(gg);
    float h = so * ftanh(c_reg);
    float h_other = __shfl(h, lane ^ 8);   // pair partner's h

    if (lane == 0) {
      // ---- DIRECT per-wave publish: 8 B agent-scope store, issued the
      // moment this wave's h pair is ready (no handshake, no relay) ----
      __hip_bfloat16 hb0 = __float2bfloat16(h);
      __hip_bfloat16 hb1 = __float2bfloat16(h_other);
      unsigned lo = (unsigned)*(unsigned short*)&hb0 |
                    ((unsigned)*(unsigned short*)&hb1 << 16);
      unsigned long long pk = ((unsigned long long)(unsigned)t << 32) |
                              (unsigned long long)lo;
      __hip_atomic_store(htag + ((t & 1) << 9) + w * 4 + v, pk,
                         __ATOMIC_RELAXED, __HIP_MEMORY_SCOPE_AGENT);
    }
    asm volatile("" ::: "memory");    // keep next-step LDS staging below publish
    if ((lane & 55) == 0) {           // lanes 0 and 8: fp32 h for CRF phase
      h_all[(size_t)t * H_DIM + w * 8 + j] = h;
    }
  }
}

// ---------------------------------------------------------------------------
// 16-lane logsumexp reduce (lanes grouped by tid&15 within a wave)
// ---------------------------------------------------------------------------
__device__ __forceinline__ float lse16(float v) {
  float m = v;
  m = fmaxf(m, __shfl_xor(m, 1));
  m = fmaxf(m, __shfl_xor(m, 2));
  m = fmaxf(m, __shfl_xor(m, 4));
  m = fmaxf(m, __shfl_xor(m, 8));
  float e = expf(v - m);
  e += __shfl_xor(e, 1);
  e += __shfl_xor(e, 2);
  e += __shfl_xor(e, 4);
  e += __shfl_xor(e, 8);
  return m + logf(e);
}

// ---------------------------------------------------------------------------
// CRF chunk kernel: per chunk c, compute feat rows s=c*64+1..c*64+64 and the
// chunk's log-semiring matrix product P_c = M_{c*64+1} x ... x M_{c*64+64}.
// M_s[i][j] = trans[i][j] + feat[s][j], feat[s] from h_all[s].
// ---------------------------------------------------------------------------
__global__ __launch_bounds__(256) void k_chunk(
    const float* __restrict__ h_all,
    const float* __restrict__ W_tag, const float* __restrict__ b_tag,
    const float* __restrict__ trans,
    float* __restrict__ featbuf,   // (T+1, 16), rows 1..T written
    float* __restrict__ Pbuf)      // (NC, 256)
{
  __shared__ float trs[16][17];
  __shared__ float featc[CLEN][16];
  __shared__ __align__(16) float hrow[H_DIM];
  __shared__ float red[16][17];
  __shared__ float Pa[16][17], Pb[16][17];

  const int tid = threadIdx.x;
  const int c = blockIdx.x;
  trs[tid >> 4][tid & 15] = trans[tid];

  // ---- feat phase ----
  const int jj = tid & 15, part = tid >> 4;
  for (int u = 0; u < CLEN; ++u) {
    int s = c * CLEN + 1 + u;
    ((float4*)hrow)[tid] = ((const float4*)(h_all + (size_t)s * H_DIM))[tid];
    __syncthreads();
    const float* wt = W_tag + (size_t)jj * H_DIM + part * 64;
    const float* hp = hrow + part * 64;
    float4 a4 = {0.f, 0.f, 0.f, 0.f};
#pragma unroll
    for (int k2 = 0; k2 < 64; k2 += 4) {
      float4 hv = *(const float4*)(hp + k2);
      float4 wv = *(const float4*)(wt + k2);
      a4.x = fmaf(hv.x, wv.x, a4.x);
      a4.y = fmaf(hv.y, wv.y, a4.y);
      a4.z = fmaf(hv.z, wv.z, a4.z);
      a4.w = fmaf(hv.w, wv.w, a4.w);
    }
    red[jj][part] = (a4.x + a4.y) + (a4.z + a4.w);
    __syncthreads();
    if (tid < 16) {
      float ssum = b_tag[tid];
#pragma unroll
      for (int pp = 0; pp < 16; ++pp) ssum += red[tid][pp];
      featc[u][tid] = ssum;
      featbuf[(size_t)s * K_TAG + tid] = ssum;
    }
    __syncthreads();
  }

  // ---- chunk product phase ----
  const int i = tid >> 4, j = tid & 15;
  Pa[i][j] = trs[i][j] + featc[0][j];
  __syncthreads();
  float* Pr = &Pa[0][0];
  float* Pw = &Pb[0][0];
  for (int u = 1; u < CLEN; ++u) {
    float fj = featc[u][j];
    float m = -3.0e38f;
#pragma unroll
    for (int k = 0; k < 16; ++k) m = fmaxf(m, Pr[i * 17 + k] + trs[k][j]);
    float e = 0.f;
#pragma unroll
    for (int k = 0; k < 16; ++k) e += expf(Pr[i * 17 + k] + trs[k][j] - m);
    Pw[i * 17 + j] = m + fj + logf(e);
    __syncthreads();
    float* tsw = Pr; Pr = Pw; Pw = tsw;
  }
  Pbuf[(size_t)c * 256 + i * 16 + j] = Pr[i * 17 + j];
}

// ---------------------------------------------------------------------------
// Sequential scan over chunk matrices (1 WG): boundary alphas + Z + alpha row 0
// ---------------------------------------------------------------------------
__global__ __launch_bounds__(256) void k_scan(
    const float* __restrict__ Pbuf,
    float* __restrict__ bbuf,      // (NC+1, 16)
    float* __restrict__ out)
{
  __shared__ float Pl[16][17];
  __shared__ float bcur[16], bnew[16];
  const int tid = threadIdx.x;
  const int i = tid & 15, j = tid >> 4;
  if (tid < 16) {
    float a0 = (tid == 0) ? 0.f : NEGINF_V;
    bcur[tid] = a0;
    bbuf[tid] = a0;
    out[1 + tid] = a0;             // alpha row 0
  }
  __syncthreads();
  for (int c = 0; c < NC; ++c) {
    Pl[tid >> 4][tid & 15] = Pbuf[(size_t)c * 256 + tid];
    __syncthreads();
    float r_ = lse16(bcur[i] + Pl[i][j]);
    if (i == 0) bnew[j] = r_;
    __syncthreads();
    if (tid < 16) {
      bcur[tid] = bnew[tid];
      bbuf[(size_t)(c + 1) * K_TAG + tid] = bnew[tid];
    }
    __syncthreads();
  }
  if (tid < 16) {
    float z = lse16(bcur[tid]);
    if (tid == 0) out[0] = z;
  }
}

// ---------------------------------------------------------------------------
// Replay within each chunk: write alpha rows s = c*64+1 .. c*64+64
// ---------------------------------------------------------------------------
__global__ __launch_bounds__(256) void k_alpha(
    const float* __restrict__ featbuf, const float* __restrict__ trans,
    const float* __restrict__ bbuf, float* __restrict__ out)
{
  __shared__ float trs[16][17];
  __shared__ float acur[16], anew[16];
  const int tid = threadIdx.x;
  const int c = blockIdx.x;
  trs[tid >> 4][tid & 15] = trans[tid];
  if (tid < 16) acur[tid] = bbuf[(size_t)c * K_TAG + tid];
  __syncthreads();
  const int i = tid & 15, j = tid >> 4;
  for (int u = 0; u < CLEN; ++u) {
    int s = c * CLEN + 1 + u;
    float v = acur[i] + trs[i][j] + featbuf[(size_t)s * K_TAG + j];
    float r_ = lse16(v);
    if (i == 0) anew[j] = r_;
    __syncthreads();
    if (tid < 16) {
      acur[tid] = anew[tid];
      out[1 + (size_t)s * K_TAG + tid] = anew[tid];
    }
    __syncthreads();
  }
}

// ---------------------------------------------------------------------------
extern "C" void kernel_launch(void* const* d_in, const int* in_sizes, int n_in,
                              void* d_out, int out_size, void* d_ws, size_t ws_size,
                              hipStream_t stream) {
  (void)in_sizes; (void)n_in; (void)out_size; (void)ws_size;
  const float* seq   = (const float*)d_in[0];
  const float* W_ih  = (const float*)d_in[1];
  const float* W_hh  = (const float*)d_in[2];
  const float* b_ih  = (const float*)d_in[3];
  const float* b_hh  = (const float*)d_in[4];
  const float* W_tag = (const float*)d_in[5];
  const float* b_tag = (const float*)d_in[6];
  const float* trans = (const float*)d_in[7];
  float* out = (float*)d_out;

  char* base = (char*)d_ws;
  size_t off = 0;
  auto take = [&](size_t nbytes) -> void* {
    void* p = base + off;
    off += (nbytes + 255) & ~(size_t)255;
    return p;
  };
  __hip_bfloat16* xg = (__hip_bfloat16*)take((size_t)T_LEN * G4 * sizeof(__hip_bfloat16));
  float* h_all   = (float*)take((size_t)(T_LEN + 1) * H_DIM * sizeof(float));
  float* featbuf = (float*)take((size_t)(T_LEN + 1) * K_TAG * sizeof(float));
  float* Pbuf    = (float*)take((size_t)NC * 256 * sizeof(float));
  float* bbuf    = (float*)take((size_t)(NC + 1) * K_TAG * sizeof(float));
  float* bsum    = (float*)take((size_t)G4 * sizeof(float));
  unsigned long long* htag = (unsigned long long*)take((size_t)2 * NPAIR * sizeof(unsigned long long));

  k_init<<<16, 256, 0, stream>>>(b_ih, b_hh, bsum, h_all, htag);
  k_gemm_xg<<<dim3(G4 / 128, T_LEN / 128), 256, 0, stream>>>(seq, W_ih, bsum, xg);
  k_lstm<<<NWG, 256, 0, stream>>>(W_hh, xg, h_all, htag);
  k_chunk<<<NC, 256, 0, stream>>>(h_all, W_tag, b_tag, trans, featbuf, Pbuf);
  k_scan<<<1, 256, 0, stream>>>(Pbuf, bbuf, out);
  k_alpha<<<NC, 256, 0, stream>>>(featbuf, trans, bbuf, out);
}

// Round 9
// 19248.582 us; speedup vs baseline: 1.2583x; 1.2583x over previous
//
#include <hip/hip_runtime.h>
#include <hip/hip_bf16.h>
#include <math.h>

#define T_LEN   8192
#define D_IN    1024
#define H_DIM   1024
#define G4      4096      // 4*H
#define K_TAG   16
#define NWG     64        // workgroups in persistent LSTM kernel (512 thr each)
#define NPAIR   512       // h exchange slots (2 bf16 per slot)
#define NC      128       // CRF chunks
#define CLEN    64        // steps per CRF chunk
#define NEGINF_V (-100000.0f)

// fast nonlinearities: __expf (native v_exp path) + fast divide.
// sigmoid: inf-safe without clamp (e=inf -> fdiv(1,inf)=0).
// tanh: clamp 2x to +-88 so e stays finite (tanh saturates anyway).
__device__ __forceinline__ float fsig(float x) {
  return __fdividef(1.f, 1.f + __expf(-x));
}
__device__ __forceinline__ float ftanh(float x) {
  float e = __expf(fminf(fmaxf(2.f * x, -88.f), 88.f));
  return __fdividef(e - 1.f, e + 1.f);
}

// ---------------------------------------------------------------------------
// init: bsum = b_ih + b_hh; h_all[0] = 0; htag[2][512] = {tag 0, 2x bf16 0}
// MUST run every launch: graph replays would otherwise see stale tags.
// ---------------------------------------------------------------------------
__global__ void k_init(const float* __restrict__ b_ih, const float* __restrict__ b_hh,
                       float* __restrict__ bsum, float* __restrict__ h0,
                       unsigned long long* __restrict__ htag) {
  int tid = blockIdx.x * 256 + threadIdx.x;
  if (tid < G4) bsum[tid] = b_ih[tid] + b_hh[tid];
  if (tid < H_DIM) h0[tid] = 0.f;
  if (tid < 2 * NPAIR) htag[tid] = 0ULL;   // tag=0, h pair = bf16 zeros
}

// ---------------------------------------------------------------------------
// GEMM: xg[t][n] = sum_d seq[t][d]*W_ih[n][d] + bsum[n], stored bf16.
// 128x128 tile, K-tile 16, 256 threads, 8x8 per thread, fp32 vector ALU.
// ---------------------------------------------------------------------------
__global__ __launch_bounds__(256) void k_gemm_xg(
    const float* __restrict__ A,      // seq   (T, D)
    const float* __restrict__ B,      // W_ih  (4H, D)
    const float* __restrict__ bsum,   // (4H)
    __hip_bfloat16* __restrict__ xg)  // (T, 4H)
{
  __shared__ __align__(16) float As[16][132];
  __shared__ __align__(16) float Bs[16][132];
  const int tid = threadIdx.x;
  const int n0 = blockIdx.x * 128;   // 32 tiles
  const int m0 = blockIdx.y * 128;   // 64 tiles
  const int ty = tid >> 4, tx = tid & 15;
  float acc[8][8] = {};

  for (int k0 = 0; k0 < D_IN; k0 += 16) {
#pragma unroll
    for (int p0 = 0; p0 < 2; ++p0) {
      int p = tid + p0 * 256;              // 0..511 float4 slots
      int row = p >> 2;
      int c4 = (p & 3) * 4;
      float4 va = *(const float4*)&A[(size_t)(m0 + row) * D_IN + k0 + c4];
      As[c4 + 0][row] = va.x; As[c4 + 1][row] = va.y;
      As[c4 + 2][row] = va.z; As[c4 + 3][row] = va.w;
      float4 vb = *(const float4*)&B[(size_t)(n0 + row) * D_IN + k0 + c4];
      Bs[c4 + 0][row] = vb.x; Bs[c4 + 1][row] = vb.y;
      Bs[c4 + 2][row] = vb.z; Bs[c4 + 3][row] = vb.w;
    }
    __syncthreads();
#pragma unroll
    for (int k = 0; k < 16; ++k) {
      float4 a0 = *(const float4*)&As[k][ty * 8];
      float4 a1 = *(const float4*)&As[k][ty * 8 + 4];
      float4 b0 = *(const float4*)&Bs[k][tx * 8];
      float4 b1 = *(const float4*)&Bs[k][tx * 8 + 4];
      float av[8] = {a0.x, a0.y, a0.z, a0.w, a1.x, a1.y, a1.z, a1.w};
      float bv[8] = {b0.x, b0.y, b0.z, b0.w, b1.x, b1.y, b1.z, b1.w};
#pragma unroll
      for (int i = 0; i < 8; ++i)
#pragma unroll
        for (int j = 0; j < 8; ++j)
          acc[i][j] = fmaf(av[i], bv[j], acc[i][j]);
    }
    __syncthreads();
  }

#pragma unroll
  for (int i = 0; i < 8; ++i) {
    size_t m = (size_t)(m0 + ty * 8 + i);
    union { __hip_bfloat16 h[8]; uint4 v; } pk;
#pragma unroll
    for (int j = 0; j < 8; ++j)
      pk.h[j] = __float2bfloat16(acc[i][j] + bsum[n0 + tx * 8 + j]);
    *(uint4*)&xg[m * G4 + n0 + tx * 8] = pk.v;
  }
}

// ---------------------------------------------------------------------------
// Persistent LSTM recurrence — R7 skeleton scaled to 64 WGs x 512 threads:
// single-wave poll, relay handshake, ONE coalesced one-line (64 B) publish
// per WG, 4-accumulator matvec (short FMA dependency chain).
//
// WG w owns h elements [w*16, w*16+16) = slots w*8..w*8+7. Wave v (0..7)
// owns elements j = 2v, 2v+1. Lane group rl8 = lane>>3 handles gate
// g = rl8>>1 of element b = rl8&1 (row = g*1024 + w*16 + 2v + b); lane
// covers columns sub*4 + 32k (k=0..31), weights in registers.
//
// Per step:
//   wave 0: poll 512 global slots (8 lane-contiguous u64 loads, s_sleep(1)
//           backoff) -> unpack to h_lds -> barrier -> matvec -> nonlin ->
//           write hxs[0] -> lanes 0-7 spin on 8 tagged LDS slots -> ONE
//           coalesced 64 B publish (exactly one line, no inter-WG line
//           sharing) -> next poll.
//   waves 1-7: barrier -> matvec -> nonlin -> ds_write hxs[v] -> fall
//           through to t+1 xg prefetch (overlaps wave 0's publish+poll).
//
// Correctness ledger (carried from R7, WG-count independent):
//  - hxs zero-init + barrier before first handshake.
//  - tag-in-word u64 slots (global AND hxs) => atomic tag+data, no fences.
//  - h_lds single-buffer safe: wave 0 restages only after all 8 hxs tags
//    = t (own waves' reads done, wave-synchronous via __shfl) and its poll
//    saw all 512 slots >= t (other WGs done).
//  - global parity double-buffer: slot can't reach tag t+1 while any
//    consumer still awaits t-1.
//  - R8 lesson kept: publish stays relayed+coalesced (direct per-wave 8 B
//    stores cost +4 ms in partial-line amplification).
// ---------------------------------------------------------------------------
__global__ __launch_bounds__(512) void k_lstm(
    const float* __restrict__ W_hh,          // (4H, H)
    const __hip_bfloat16* __restrict__ xg,   // (T, 4H)
    float* __restrict__ h_all,               // (T+1, H) plain, for CRF kernels
    unsigned long long* __restrict__ htag)   // (2, 512) tagged bf16-pair slots
{
  __shared__ __align__(16) float h_lds[H_DIM];
  __shared__ unsigned long long hxs[8];      // per-wave {tag, bf16 pair}

  const int tid = threadIdx.x;
  const int w = blockIdx.x;
  const int lane = tid & 63;
  const int v = tid >> 6;                   // wave id 0..7
  const int rl8 = lane >> 3;                // 0..7
  const int sub = lane & 7;                 // 0..7 column chunk
  const int g = rl8 >> 1, b = rl8 & 1;
  const int j = 2 * v + b;                  // element within 16-slice
  const int grow = g * H_DIM + w * 16 + j;  // gate row in (4H)

  float4 w4[32];
#pragma unroll
  for (int k = 0; k < 32; ++k)
    w4[k] = *(const float4*)&W_hh[(size_t)grow * H_DIM + sub * 4 + 32 * k];

  if (tid < 8) hxs[tid] = 0ULL;   // kill stale LDS before first handshake
  __syncthreads();

  float c_reg = 0.f;   // cell state, redundantly maintained by all lanes

  for (int t = 1; t <= T_LEN; ++t) {
    // prefetch this step's input-gate term (independent of exchange;
    // for waves 1-7 this issues while wave 0 still publishes/polls)
    float xgv = __bfloat162float(xg[(size_t)(t - 1) * G4 + grow]);

    if (v == 0) {
      // ---- wave 0: poll all 512 tagged slots of parity (t-1)&1 ----
      unsigned long long* hb = htag + (((t - 1) & 1) << 9);
      const unsigned tgt = (unsigned)(t - 1);
      unsigned long long x0, x1, x2, x3, x4, x5, x6, x7;
      for (;;) {
        x0 = __hip_atomic_load(hb + lane,       __ATOMIC_RELAXED, __HIP_MEMORY_SCOPE_AGENT);
        x1 = __hip_atomic_load(hb + lane + 64,  __ATOMIC_RELAXED, __HIP_MEMORY_SCOPE_AGENT);
        x2 = __hip_atomic_load(hb + lane + 128, __ATOMIC_RELAXED, __HIP_MEMORY_SCOPE_AGENT);
        x3 = __hip_atomic_load(hb + lane + 192, __ATOMIC_RELAXED, __HIP_MEMORY_SCOPE_AGENT);
        x4 = __hip_atomic_load(hb + lane + 256, __ATOMIC_RELAXED, __HIP_MEMORY_SCOPE_AGENT);
        x5 = __hip_atomic_load(hb + lane + 320, __ATOMIC_RELAXED, __HIP_MEMORY_SCOPE_AGENT);
        x6 = __hip_atomic_load(hb + lane + 384, __ATOMIC_RELAXED, __HIP_MEMORY_SCOPE_AGENT);
        x7 = __hip_atomic_load(hb + lane + 448, __ATOMIC_RELAXED, __HIP_MEMORY_SCOPE_AGENT);
        unsigned mn = min(min(min((unsigned)(x0 >> 32), (unsigned)(x1 >> 32)),
                              min((unsigned)(x2 >> 32), (unsigned)(x3 >> 32))),
                          min(min((unsigned)(x4 >> 32), (unsigned)(x5 >> 32)),
                              min((unsigned)(x6 >> 32), (unsigned)(x7 >> 32))));
        if (mn >= tgt) break;
        __builtin_amdgcn_s_sleep(1);
      }
      // unpack bf16 pairs -> h_lds (float2 per slot; 2-way bank alias, free)
      unsigned long long xs[8] = {x0, x1, x2, x3, x4, x5, x6, x7};
#pragma unroll
      for (int i = 0; i < 8; ++i) {
        unsigned lo = (unsigned)xs[i];
        unsigned short s0 = (unsigned short)lo;
        unsigned short s1 = (unsigned short)(lo >> 16);
        float2 p;
        p.x = __bfloat162float(*(const __hip_bfloat16*)&s0);
        p.y = __bfloat162float(*(const __hip_bfloat16*)&s1);
        ((float2*)h_lds)[lane + 64 * i] = p;
      }
    }
    __syncthreads();   // barrier: h_{t-1} staged, previous handshake consumed

    // ---- matvec: 128 columns per thread, 4 independent FMA chains ----
    const float4* h4 = (const float4*)h_lds;
    float ac0 = 0.f, ac1 = 0.f, ac2 = 0.f, ac3 = 0.f;
#pragma unroll
    for (int k = 0; k < 32; k += 4) {
      float4 hv0 = h4[sub + 8 * k];
      float4 hv1 = h4[sub + 8 * (k + 1)];
      float4 hv2 = h4[sub + 8 * (k + 2)];
      float4 hv3 = h4[sub + 8 * (k + 3)];
      ac0 = fmaf(w4[k].x, hv0.x, ac0);
      ac0 = fmaf(w4[k].y, hv0.y, ac0);
      ac0 = fmaf(w4[k].z, hv0.z, ac0);
      ac0 = fmaf(w4[k].w, hv0.w, ac0);
      ac1 = fmaf(w4[k + 1].x, hv1.x, ac1);
      ac1 = fmaf(w4[k + 1].y, hv1.y, ac1);
      ac1 = fmaf(w4[k + 1].z, hv1.z, ac1);
      ac1 = fmaf(w4[k + 1].w, hv1.w, ac1);
      ac2 = fmaf(w4[k + 2].x, hv2.x, ac2);
      ac2 = fmaf(w4[k + 2].y, hv2.y, ac2);
      ac2 = fmaf(w4[k + 2].z, hv2.z, ac2);
      ac2 = fmaf(w4[k + 2].w, hv2.w, ac2);
      ac3 = fmaf(w4[k + 3].x, hv3.x, ac3);
      ac3 = fmaf(w4[k + 3].y, hv3.y, ac3);
      ac3 = fmaf(w4[k + 3].z, hv3.z, ac3);
      ac3 = fmaf(w4[k + 3].w, hv3.w, ac3);
    }
    float acc = (ac0 + ac1) + (ac2 + ac3);
    acc += __shfl_xor(acc, 1);
    acc += __shfl_xor(acc, 2);
    acc += __shfl_xor(acc, 4);
    acc += xgv;                       // all 8 lanes of the group hold the gate

    // ---- gather i,f,g,o of this lane's element (b = (lane>>3)&1) ----
    const int bl = lane & 8;
    float gi = __shfl(acc, bl);
    float gf = __shfl(acc, bl | 16);
    float gg = __shfl(acc, bl | 32);
    float go = __shfl(acc, bl | 48);

    float si = fsig(gi);
    float sf = fsig(gf);
    float so = fsig(go);
    c_reg = sf * c_reg + si * ftanh(gg);
    float h = so * ftanh(c_reg);
    float h_other = __shfl(h, lane ^ 8);   // pair partner's h

    if (lane == 0) {                  // lane 0 of each wave: tagged LDS stage
      __hip_bfloat16 hb0 = __float2bfloat16(h);
      __hip_bfloat16 hb1 = __float2bfloat16(h_other);
      unsigned lo = (unsigned)*(unsigned short*)&hb0 |
                    ((unsigned)*(unsigned short*)&hb1 << 16);
      unsigned long long pk = ((unsigned long long)(unsigned)t << 32) |
                              (unsigned long long)lo;
      __hip_atomic_store(&hxs[v], pk, __ATOMIC_RELAXED, __HIP_MEMORY_SCOPE_WORKGROUP);
    }
    if ((lane & 55) == 0) {           // lanes 0 and 8: fp32 h for CRF phase
      h_all[(size_t)t * H_DIM + w * 16 + j] = h;
    }

    if (v == 0 && lane < 8) {
      // ---- 8-lane tagged handshake (tiny LDS spin), then ONE 64 B publish
      // (exactly one line per WG; no inter-WG line sharing) ----
      unsigned long long pk;
      do {
        pk = __hip_atomic_load(&hxs[lane], __ATOMIC_RELAXED, __HIP_MEMORY_SCOPE_WORKGROUP);
      } while ((unsigned)(pk >> 32) != (unsigned)t);
      __hip_atomic_store(htag + ((t & 1) << 9) + w * 8 + lane, pk,
                         __ATOMIC_RELAXED, __HIP_MEMORY_SCOPE_AGENT);
    }
    // waves 1-7 fall through to t+1 (xg prefetch + barrier wait);
    // wave 0's next-step staging is the only h_lds writer and it happens
    // strictly after all hxs tags reached t.
  }
}

// ---------------------------------------------------------------------------
// 16-lane logsumexp reduce (lanes grouped by tid&15 within a wave)
// ---------------------------------------------------------------------------
__device__ __forceinline__ float lse16(float v) {
  float m = v;
  m = fmaxf(m, __shfl_xor(m, 1));
  m = fmaxf(m, __shfl_xor(m, 2));
  m = fmaxf(m, __shfl_xor(m, 4));
  m = fmaxf(m, __shfl_xor(m, 8));
  float e = expf(v - m);
  e += __shfl_xor(e, 1);
  e += __shfl_xor(e, 2);
  e += __shfl_xor(e, 4);
  e += __shfl_xor(e, 8);
  return m + logf(e);
}

// ---------------------------------------------------------------------------
// CRF chunk kernel: per chunk c, compute feat rows s=c*64+1..c*64+64 and the
// chunk's log-semiring matrix product P_c = M_{c*64+1} x ... x M_{c*64+64}.
// M_s[i][j] = trans[i][j] + feat[s][j], feat[s] from h_all[s].
// ---------------------------------------------------------------------------
__global__ __launch_bounds__(256) void k_chunk(
    const float* __restrict__ h_all,
    const float* __restrict__ W_tag, const float* __restrict__ b_tag,
    const float* __restrict__ trans,
    float* __restrict__ featbuf,   // (T+1, 16), rows 1..T written
    float* __restrict__ Pbuf)      // (NC, 256)
{
  __shared__ float trs[16][17];
  __shared__ float featc[CLEN][16];
  __shared__ __align__(16) float hrow[H_DIM];
  __shared__ float red[16][17];
  __shared__ float Pa[16][17], Pb[16][17];

  const int tid = threadIdx.x;
  const int c = blockIdx.x;
  trs[tid >> 4][tid & 15] = trans[tid];

  // ---- feat phase ----
  const int jj = tid & 15, part = tid >> 4;
  for (int u = 0; u < CLEN; ++u) {
    int s = c * CLEN + 1 + u;
    ((float4*)hrow)[tid] = ((const float4*)(h_all + (size_t)s * H_DIM))[tid];
    __syncthreads();
    const float* wt = W_tag + (size_t)jj * H_DIM + part * 64;
    const float* hp = hrow + part * 64;
    float4 a4 = {0.f, 0.f, 0.f, 0.f};
#pragma unroll
    for (int k2 = 0; k2 < 64; k2 += 4) {
      float4 hv = *(const float4*)(hp + k2);
      float4 wv = *(const float4*)(wt + k2);
      a4.x = fmaf(hv.x, wv.x, a4.x);
      a4.y = fmaf(hv.y, wv.y, a4.y);
      a4.z = fmaf(hv.z, wv.z, a4.z);
      a4.w = fmaf(hv.w, wv.w, a4.w);
    }
    red[jj][part] = (a4.x + a4.y) + (a4.z + a4.w);
    __syncthreads();
    if (tid < 16) {
      float ssum = b_tag[tid];
#pragma unroll
      for (int pp = 0; pp < 16; ++pp) ssum += red[tid][pp];
      featc[u][tid] = ssum;
      featbuf[(size_t)s * K_TAG + tid] = ssum;
    }
    __syncthreads();
  }

  // ---- chunk product phase ----
  const int i = tid >> 4, j = tid & 15;
  Pa[i][j] = trs[i][j] + featc[0][j];
  __syncthreads();
  float* Pr = &Pa[0][0];
  float* Pw = &Pb[0][0];
  for (int u = 1; u < CLEN; ++u) {
    float fj = featc[u][j];
    float m = -3.0e38f;
#pragma unroll
    for (int k = 0; k < 16; ++k) m = fmaxf(m, Pr[i * 17 + k] + trs[k][j]);
    float e = 0.f;
#pragma unroll
    for (int k = 0; k < 16; ++k) e += expf(Pr[i * 17 + k] + trs[k][j] - m);
    Pw[i * 17 + j] = m + fj + logf(e);
    __syncthreads();
    float* tsw = Pr; Pr = Pw; Pw = tsw;
  }
  Pbuf[(size_t)c * 256 + i * 16 + j] = Pr[i * 17 + j];
}

// ---------------------------------------------------------------------------
// Sequential scan over chunk matrices (1 WG): boundary alphas + Z + alpha row 0
// ---------------------------------------------------------------------------
__global__ __launch_bounds__(256) void k_scan(
    const float* __restrict__ Pbuf,
    float* __restrict__ bbuf,      // (NC+1, 16)
    float* __restrict__ out)
{
  __shared__ float Pl[16][17];
  __shared__ float bcur[16], bnew[16];
  const int tid = threadIdx.x;
  const int i = tid & 15, j = tid >> 4;
  if (tid < 16) {
    float a0 = (tid == 0) ? 0.f : NEGINF_V;
    bcur[tid] = a0;
    bbuf[tid] = a0;
    out[1 + tid] = a0;             // alpha row 0
  }
  __syncthreads();
  for (int c = 0; c < NC; ++c) {
    Pl[tid >> 4][tid & 15] = Pbuf[(size_t)c * 256 + tid];
    __syncthreads();
    float r_ = lse16(bcur[i] + Pl[i][j]);
    if (i == 0) bnew[j] = r_;
    __syncthreads();
    if (tid < 16) {
      bcur[tid] = bnew[tid];
      bbuf[(size_t)(c + 1) * K_TAG + tid] = bnew[tid];
    }
    __syncthreads();
  }
  if (tid < 16) {
    float z = lse16(bcur[tid]);
    if (tid == 0) out[0] = z;
  }
}

// ---------------------------------------------------------------------------
// Replay within each chunk: write alpha rows s = c*64+1 .. c*64+64
// ---------------------------------------------------------------------------
__global__ __launch_bounds__(256) void k_alpha(
    const float* __restrict__ featbuf, const float* __restrict__ trans,
    const float* __restrict__ bbuf, float* __restrict__ out)
{
  __shared__ float trs[16][17];
  __shared__ float acur[16], anew[16];
  const int tid = threadIdx.x;
  const int c = blockIdx.x;
  trs[tid >> 4][tid & 15] = trans[tid];
  if (tid < 16) acur[tid] = bbuf[(size_t)c * K_TAG + tid];
  __syncthreads();
  const int i = tid & 15, j = tid >> 4;
  for (int u = 0; u < CLEN; ++u) {
    int s = c * CLEN + 1 + u;
    float v = acur[i] + trs[i][j] + featbuf[(size_t)s * K_TAG + j];
    float r_ = lse16(v);
    if (i == 0) anew[j] = r_;
    __syncthreads();
    if (tid < 16) {
      acur[tid] = anew[tid];
      out[1 + (size_t)s * K_TAG + tid] = anew[tid];
    }
    __syncthreads();
  }
}

// ---------------------------------------------------------------------------
extern "C" void kernel_launch(void* const* d_in, const int* in_sizes, int n_in,
                              void* d_out, int out_size, void* d_ws, size_t ws_size,
                              hipStream_t stream) {
  (void)in_sizes; (void)n_in; (void)out_size; (void)ws_size;
  const float* seq   = (const float*)d_in[0];
  const float* W_ih  = (const float*)d_in[1];
  const float* W_hh  = (const float*)d_in[2];
  const float* b_ih  = (const float*)d_in[3];
  const float* b_hh  = (const float*)d_in[4];
  const float* W_tag = (const float*)d_in[5];
  const float* b_tag = (const float*)d_in[6];
  const float* trans = (const float*)d_in[7];
  float* out = (float*)d_out;

  char* base = (char*)d_ws;
  size_t off = 0;
  auto take = [&](size_t nbytes) -> void* {
    void* p = base + off;
    off += (nbytes + 255) & ~(size_t)255;
    return p;
  };
  __hip_bfloat16* xg = (__hip_bfloat16*)take((size_t)T_LEN * G4 * sizeof(__hip_bfloat16));
  float* h_all   = (float*)take((size_t)(T_LEN + 1) * H_DIM * sizeof(float));
  float* featbuf = (float*)take((size_t)(T_LEN + 1) * K_TAG * sizeof(float));
  float* Pbuf    = (float*)take((size_t)NC * 256 * sizeof(float));
  float* bbuf    = (float*)take((size_t)(NC + 1) * K_TAG * sizeof(float));
  float* bsum    = (float*)take((size_t)G4 * sizeof(float));
  unsigned long long* htag = (unsigned long long*)take((size_t)2 * NPAIR * sizeof(unsigned long long));

  k_init<<<16, 256, 0, stream>>>(b_ih, b_hh, bsum, h_all, htag);
  k_gemm_xg<<<dim3(G4 / 128, T_LEN / 128), 256, 0, stream>>>(seq, W_ih, bsum, xg);
  k_lstm<<<NWG, 512, 0, stream>>>(W_hh, xg, h_all, htag);
  k_chunk<<<NC, 256, 0, stream>>>(h_all, W_tag, b_tag, trans, featbuf, Pbuf);
  k_scan<<<1, 256, 0, stream>>>(Pbuf, bbuf, out);
  k_alpha<<<NC, 256, 0, stream>>>(featbuf, trans, bbuf, out);
}